// Round 1
// baseline (1692.620 us; speedup 1.0000x reference)
//
#include <hip/hip_runtime.h>
#include <math.h>

#define NN 100000
#define CH 128
#define HH 64

// ---------------- CSR build ----------------
__global__ void count_kernel(const int* __restrict__ dst, int* __restrict__ cnt, int E) {
    int i = blockIdx.x * blockDim.x + threadIdx.x;
    if (i < E) atomicAdd(&cnt[dst[i]], 1);
}

__global__ __launch_bounds__(1024) void scan_kernel(const int* __restrict__ cnt,
                                                    int* __restrict__ row,
                                                    int* __restrict__ cur,
                                                    int n, int total) {
    __shared__ int tsum[1024];
    const int t = threadIdx.x;
    const int chunk = (n + 1023) / 1024;
    const int lo = t * chunk;
    const int hi = (lo + chunk < n) ? (lo + chunk) : n;
    int s = 0;
    for (int i = lo; i < hi; ++i) s += cnt[i];
    tsum[t] = s;
    __syncthreads();
    // Hillis-Steele inclusive scan
    for (int off = 1; off < 1024; off <<= 1) {
        int v = (t >= off) ? tsum[t - off] : 0;
        __syncthreads();
        tsum[t] += v;
        __syncthreads();
    }
    int run = (t == 0) ? 0 : tsum[t - 1];
    for (int i = lo; i < hi; ++i) {
        row[i] = run;
        cur[i] = run;
        run += cnt[i];
    }
    if (t == 1023) row[n] = total;
}

__global__ void fill_kernel(const int* __restrict__ src, const int* __restrict__ dst,
                            int* __restrict__ cur, int* __restrict__ csr, int E) {
    int i = blockIdx.x * blockDim.x + threadIdx.x;
    if (i < E) {
        int p = atomicAdd(&cur[dst[i]], 1);
        csr[p] = src[i];
    }
}

// ---------------- fused layer ----------------
// segment-mean of 128-ch rows; lane handles channels 2*lane, 2*lane+1
__device__ __forceinline__ float2 agg_seg(const float* __restrict__ feat,
                                          const int* __restrict__ csr,
                                          int s0, int s1, int lane) {
    float ax = 0.f, ay = 0.f;
    int e = s0;
    for (; e + 1 < s1; e += 2) {
        int a = csr[e], b = csr[e + 1];
        float2 va = ((const float2*)(feat + (size_t)a * CH))[lane];
        float2 vb = ((const float2*)(feat + (size_t)b * CH))[lane];
        ax += va.x + vb.x;
        ay += va.y + vb.y;
    }
    if (e < s1) {
        int a = csr[e];
        float2 va = ((const float2*)(feat + (size_t)a * CH))[lane];
        ax += va.x;
        ay += va.y;
    }
    int d = s1 - s0;
    float inv = 1.0f / (float)(d > 1 ? d : 1);
    return make_float2(ax * inv, ay * inv);
}

// Block = 256 threads = 4 waves, handles 8 nodes.
// Phase 1: wave w aggregates nodes base+2w, base+2w+1 (pos & neg, full 128 ch) into LDS.
// Phase 2: wave w -> (group g = w>>1 of 4 nodes, half = w&1 of output cols),
//          lane j computes 4 nodes' output column (half*64 + j) with fp32 dots + tanh.
template <bool L0>
__global__ __launch_bounds__(256) void layer_kernel(
    const float* __restrict__ feat, float* __restrict__ out,
    const int* __restrict__ row_p, const int* __restrict__ csr_p,
    const int* __restrict__ row_n, const int* __restrict__ csr_n,
    const float* __restrict__ W0,  // L0: Wp_l (128x64)  | gen: Wl_pos (128x64)
    const float* __restrict__ W1,  // L0: Wp_r (128x64)  | gen: Wr_pos (64x64)
    const float* __restrict__ b0,  // bp | b_pos
    const float* __restrict__ W2,  // L0: Wn_l | gen: Wl_neg
    const float* __restrict__ W3,  // L0: Wn_r | gen: Wr_neg
    const float* __restrict__ b1,  // bn | b_neg
    int nN) {
    __shared__ float agg[2][8][CH];  // [pos/neg][node][ch]
    __shared__ float xr[8][CH];      // own features

    const int t = threadIdx.x;
    const int wave = t >> 6;
    const int lane = t & 63;
    const int base = blockIdx.x * 8;

    // ---- Phase 1: aggregation ----
#pragma unroll
    for (int i = 0; i < 2; ++i) {
        const int m = wave * 2 + i;
        const int node = base + m;
        if (node < nN) {
            float2 xv = ((const float2*)(feat + (size_t)node * CH))[lane];
            ((float2*)&xr[m][0])[lane] = xv;
            int p0 = row_p[node], p1 = row_p[node + 1];
            float2 apv = agg_seg(feat, csr_p, p0, p1, lane);
            ((float2*)&agg[0][m][0])[lane] = apv;
            int q0 = row_n[node], q1 = row_n[node + 1];
            float2 anv = agg_seg(feat, csr_n, q0, q1, lane);
            ((float2*)&agg[1][m][0])[lane] = anv;
        }
    }
    __syncthreads();

    // ---- Phase 2: matmul + tanh ----
    const int g = wave >> 1;
    const int half = wave & 1;
    const int j = lane;
    const float* __restrict__ Wa = half ? W2 : W0;
    const float* __restrict__ Wx = half ? W3 : W1;
    const float* __restrict__ bb = half ? b1 : b0;

    float o[4];
    const float bj = bb[j];
#pragma unroll
    for (int m = 0; m < 4; ++m) o[m] = bj;

    if (L0) {
#pragma unroll 2
        for (int k = 0; k < CH; ++k) {
            float wa = Wa[k * HH + j];
            float wx = Wx[k * HH + j];
#pragma unroll
            for (int m = 0; m < 4; ++m) {
                const int nm = g * 4 + m;
                o[m] += agg[half][nm][k] * wa + xr[nm][k] * wx;
            }
        }
    } else {
        const int offA = half * HH;        // ap offset
        const int offB = HH - offA;        // an offset
#pragma unroll 2
        for (int k = 0; k < HH; ++k) {
            float w1 = Wa[k * HH + j];
            float w2 = Wa[(HH + k) * HH + j];
            float wx = Wx[k * HH + j];
#pragma unroll
            for (int m = 0; m < 4; ++m) {
                const int nm = g * 4 + m;
                o[m] += agg[0][nm][offA + k] * w1 + agg[1][nm][offB + k] * w2 +
                        xr[nm][offA + k] * wx;
            }
        }
    }

#pragma unroll
    for (int m = 0; m < 4; ++m) {
        const int node = base + g * 4 + m;
        if (node < nN) out[(size_t)node * CH + half * HH + j] = tanhf(o[m]);
    }
}

// ---------------- launch ----------------
extern "C" void kernel_launch(void* const* d_in, const int* in_sizes, int n_in,
                              void* d_out, int out_size, void* d_ws, size_t ws_size,
                              hipStream_t stream) {
    const float* x      = (const float*)d_in[0];
    const int*   pe     = (const int*)d_in[1];   // [2][E] src,dst
    const int*   ne     = (const int*)d_in[2];
    const float* Wp_l   = (const float*)d_in[3];
    const float* Wp_r   = (const float*)d_in[4];
    const float* bp     = (const float*)d_in[5];
    const float* Wn_l   = (const float*)d_in[6];
    const float* Wn_r   = (const float*)d_in[7];
    const float* bn     = (const float*)d_in[8];
    const float* Wl_pos = (const float*)d_in[9];
    const float* Wr_pos = (const float*)d_in[10];
    const float* b_pos  = (const float*)d_in[11];
    const float* Wl_neg = (const float*)d_in[12];
    const float* Wr_neg = (const float*)d_in[13];
    const float* b_neg  = (const float*)d_in[14];

    const int E = in_sizes[1] / 2;
    const int n = in_sizes[0] / CH;

    // workspace layout
    float* z0    = (float*)d_ws;                 // n*CH floats
    int*   cnt_p = (int*)(z0 + (size_t)n * CH);  // n
    int*   cnt_n = cnt_p + n;                    // n
    int*   row_p = cnt_n + n;                    // n+1
    int*   row_n = row_p + n + 1;                // n+1
    int*   cur_p = row_n + n + 1;                // n
    int*   cur_n = cur_p + n;                    // n
    int*   csr_p = cur_n + n;                    // E
    int*   csr_n = csr_p + E;                    // E

    hipMemsetAsync(cnt_p, 0, (size_t)2 * n * sizeof(int), stream);

    const int eb = 256, eg = (E + eb - 1) / eb;
    count_kernel<<<eg, eb, 0, stream>>>(pe + E, cnt_p, E);
    count_kernel<<<eg, eb, 0, stream>>>(ne + E, cnt_n, E);
    scan_kernel<<<1, 1024, 0, stream>>>(cnt_p, row_p, cur_p, n, E);
    scan_kernel<<<1, 1024, 0, stream>>>(cnt_n, row_n, cur_n, n, E);
    fill_kernel<<<eg, eb, 0, stream>>>(pe, pe + E, cur_p, csr_p, E);
    fill_kernel<<<eg, eb, 0, stream>>>(ne, ne + E, cur_n, csr_n, E);

    float* zout = (float*)d_out;
    dim3 grid((n + 7) / 8);
    dim3 block(256);

    // Layer 0: x -> d_out
    layer_kernel<true><<<grid, block, 0, stream>>>(
        x, zout, row_p, csr_p, row_n, csr_n, Wp_l, Wp_r, bp, Wn_l, Wn_r, bn, n);
    // Layer 1: d_out -> z0
    layer_kernel<false><<<grid, block, 0, stream>>>(
        zout, z0, row_p, csr_p, row_n, csr_n,
        Wl_pos, Wr_pos, b_pos, Wl_neg, Wr_neg, b_neg, n);
    // Layer 2: z0 -> d_out
    layer_kernel<false><<<grid, block, 0, stream>>>(
        z0, zout, row_p, csr_p, row_n, csr_n,
        Wl_pos + CH * HH, Wr_pos + HH * HH, b_pos + HH,
        Wl_neg + CH * HH, Wr_neg + HH * HH, b_neg + HH, n);
}

// Round 2
// 1571.526 us; speedup vs baseline: 1.0771x; 1.0771x over previous
//
#include <hip/hip_runtime.h>
#include <math.h>

#define CH 128
#define HH 64
#define SCAN_T 256
#define SCAN_I 4
#define SCAN_CHUNK (SCAN_T * SCAN_I)

// ---------------- CSR build ----------------
// pos and neg fused: i < E -> pos, else neg
__global__ void count_kernel(const int* __restrict__ pd, const int* __restrict__ nd,
                             int* __restrict__ cnt_p, int* __restrict__ cnt_n, int E) {
    int i = blockIdx.x * blockDim.x + threadIdx.x;
    if (i < E) atomicAdd(&cnt_p[pd[i]], 1);
    else if (i < 2 * E) atomicAdd(&cnt_n[nd[i - E]], 1);
}

__global__ void fill_kernel(const int* __restrict__ pe, const int* __restrict__ ne,
                            int* __restrict__ cur_p, int* __restrict__ cur_n,
                            int* __restrict__ csr_p, int* __restrict__ csr_n, int E) {
    int i = blockIdx.x * blockDim.x + threadIdx.x;
    if (i < E) {
        int p = atomicAdd(&cur_p[pe[E + i]], 1);
        csr_p[p] = pe[i];
    } else if (i < 2 * E) {
        int k = i - E;
        int p = atomicAdd(&cur_n[ne[E + k]], 1);
        csr_n[p] = ne[k];
    }
}

// stage 1: per-block (1024-elem chunk) sums; grid (nb, 2)
__global__ __launch_bounds__(SCAN_T) void partial_kernel(const int* __restrict__ cnt, int n,
                                                         int* __restrict__ partials) {
    const int y = blockIdx.y, b = blockIdx.x, t = threadIdx.x;
    const int* c = cnt + (size_t)y * n;
    const int base = b * SCAN_CHUNK + t * SCAN_I;
    int s = 0;
    if (base + SCAN_I <= n) {
        int4 v = *(const int4*)(c + base);
        s = v.x + v.y + v.z + v.w;
    } else {
        for (int i = 0; i < SCAN_I; ++i)
            if (base + i < n) s += c[base + i];
    }
    __shared__ int red[SCAN_T];
    red[t] = s;
    __syncthreads();
    for (int off = SCAN_T / 2; off > 0; off >>= 1) {
        if (t < off) red[t] += red[t + off];
        __syncthreads();
    }
    if (t == 0) partials[y * 256 + b] = red[0];
}

// stage 2: exclusive scan of <=256 partials; grid (1, 2)
__global__ __launch_bounds__(256) void scan_partials_kernel(int* __restrict__ partials, int nb) {
    const int y = blockIdx.y, t = threadIdx.x;
    int* p = partials + y * 256;
    __shared__ int sh[256];
    sh[t] = (t < nb) ? p[t] : 0;
    __syncthreads();
    for (int off = 1; off < 256; off <<= 1) {
        int v = (t >= off) ? sh[t - off] : 0;
        __syncthreads();
        sh[t] += v;
        __syncthreads();
    }
    if (t < nb) p[t] = (t == 0) ? 0 : sh[t - 1];
}

// stage 3: block-local scan + partial offset -> row, cur; grid (nb, 2)
__global__ __launch_bounds__(SCAN_T) void scan_apply_kernel(const int* __restrict__ cnt, int n,
                                                            const int* __restrict__ partials,
                                                            int* __restrict__ row,
                                                            int* __restrict__ cur, int total) {
    const int y = blockIdx.y, b = blockIdx.x, t = threadIdx.x;
    const int* c = cnt + (size_t)y * n;
    int* r = row + (size_t)y * (n + 1);
    int* q = cur + (size_t)y * n;
    const int base = b * SCAN_CHUNK + t * SCAN_I;
    int v0 = 0, v1 = 0, v2 = 0, v3 = 0;
    const bool full = (base + SCAN_I <= n);
    if (full) {
        int4 vv = *(const int4*)(c + base);
        v0 = vv.x; v1 = vv.y; v2 = vv.z; v3 = vv.w;
    } else {
        if (base + 0 < n) v0 = c[base + 0];
        if (base + 1 < n) v1 = c[base + 1];
        if (base + 2 < n) v2 = c[base + 2];
        if (base + 3 < n) v3 = c[base + 3];
    }
    const int s = v0 + v1 + v2 + v3;
    __shared__ int sh[SCAN_T];
    sh[t] = s;
    __syncthreads();
    for (int off = 1; off < SCAN_T; off <<= 1) {
        int v = (t >= off) ? sh[t - off] : 0;
        __syncthreads();
        sh[t] += v;
        __syncthreads();
    }
    int run = partials[y * 256 + b] + sh[t] - s;  // exclusive prefix
    if (full) {
        int4 rv;
        rv.x = run; rv.y = run + v0; rv.z = run + v0 + v1; rv.w = run + v0 + v1 + v2;
        *(int4*)(r + base) = rv;
        *(int4*)(q + base) = rv;
    } else {
        if (base + 0 < n) { r[base + 0] = run; q[base + 0] = run; run += v0; }
        if (base + 1 < n) { r[base + 1] = run; q[base + 1] = run; run += v1; }
        if (base + 2 < n) { r[base + 2] = run; q[base + 2] = run; run += v2; }
        if (base + 3 < n) { r[base + 3] = run; q[base + 3] = run; run += v3; }
    }
    if (b == 0 && t == 0) r[n] = total;
}

// ---------------- fused layer ----------------
__device__ __forceinline__ float fast_tanh(float x) {
    // tanh(x) = 1 - 2/(exp(2x)+1); exp->v_exp_f32, rcp->v_rcp_f32 (~5 VALU vs ~20 for libm)
    float e = __expf(2.0f * x);
    return 1.0f - 2.0f * __builtin_amdgcn_rcpf(e + 1.0f);
}

// Block = 256 threads = 4 waves, 8 nodes.
// Phase 1: lane l handles edge e + (l>>5), channels 4*(l&31).. (+3): one
//          global_load_dwordx4 fetches TWO full 512B edge rows per wave.
//          Halves combined with shfl_xor(32).
// Phase 2: wave -> (group g of 4 nodes, half of output cols); lane j = out col.
//          k-blocked by 4: wave-uniform ds_read_b128 (LDS broadcast) + 4 hoisted
//          weights per array, 12 FMAs per node per k-block.
template <bool L0>
__global__ __launch_bounds__(256) void layer_kernel(
    const float* __restrict__ feat, float* __restrict__ out,
    const int* __restrict__ row_p, const int* __restrict__ csr_p,
    const int* __restrict__ row_n, const int* __restrict__ csr_n,
    const float* __restrict__ W0, const float* __restrict__ W1, const float* __restrict__ b0,
    const float* __restrict__ W2, const float* __restrict__ W3, const float* __restrict__ b1,
    int nN) {
    __shared__ __align__(16) float agg[2][8][CH];
    __shared__ __align__(16) float xr[8][CH];

    const int t = threadIdx.x;
    const int wave = t >> 6;
    const int lane = t & 63;
    const int sub = lane >> 5;        // which edge of the pair
    const int c4 = (lane & 31) << 2;  // channel base (float4)
    const int base = blockIdx.x * 8;

    // own rows: the two sub-halves load the wave's two nodes' own features
    {
        const int m = wave * 2 + sub;
        const int node = base + m;
        if (node < nN) {
            const float4 v = *(const float4*)(feat + (size_t)node * CH + c4);
            *(float4*)&xr[m][c4] = v;
        }
    }

    // ---- Phase 1: aggregation ----
#pragma unroll
    for (int i = 0; i < 2; ++i) {
        const int m = wave * 2 + i;
        const int node = base + m;
        if (node < nN) {
#pragma unroll
            for (int s = 0; s < 2; ++s) {
                const int* __restrict__ rowp = s ? row_n : row_p;
                const int* __restrict__ csr = s ? csr_n : csr_p;
                const int s0 = rowp[node], s1 = rowp[node + 1];
                float ax = 0.f, ay = 0.f, az = 0.f, aw = 0.f;
                const int e1 = s0 + ((s1 - s0) & ~1);
                for (int e = s0; e < e1; e += 2) {
                    const int a = csr[e + sub];
                    const float4 v = *(const float4*)(feat + (size_t)a * CH + c4);
                    ax += v.x; ay += v.y; az += v.z; aw += v.w;
                }
                if (((s1 - s0) & 1) && sub == 0) {
                    const int a = csr[s1 - 1];
                    const float4 v = *(const float4*)(feat + (size_t)a * CH + c4);
                    ax += v.x; ay += v.y; az += v.z; aw += v.w;
                }
                ax += __shfl_xor(ax, 32);
                ay += __shfl_xor(ay, 32);
                az += __shfl_xor(az, 32);
                aw += __shfl_xor(aw, 32);
                const int d = s1 - s0;
                const float inv = 1.0f / (float)(d > 1 ? d : 1);
                if (sub == 0)
                    *(float4*)&agg[s][m][c4] = make_float4(ax * inv, ay * inv, az * inv, aw * inv);
            }
        }
    }
    __syncthreads();

    // ---- Phase 2: matmul + tanh ----
    const int g = wave >> 1;
    const int half = wave & 1;
    const int j = lane;
    const float* __restrict__ Wa = half ? W2 : W0;
    const float* __restrict__ Wx = half ? W3 : W1;
    const float* __restrict__ bb = half ? b1 : b0;

    float o[4];
    const float bj = bb[j];
#pragma unroll
    for (int m = 0; m < 4; ++m) o[m] = bj;

    if (L0) {
#pragma unroll 4
        for (int kb = 0; kb < CH; kb += 4) {
            float wa[4], wx[4];
#pragma unroll
            for (int kk = 0; kk < 4; ++kk) {
                wa[kk] = Wa[(kb + kk) * HH + j];
                wx[kk] = Wx[(kb + kk) * HH + j];
            }
#pragma unroll
            for (int m = 0; m < 4; ++m) {
                const int nm = g * 4 + m;
                const float4 av = *(const float4*)&agg[half][nm][kb];
                const float4 xv = *(const float4*)&xr[nm][kb];
                o[m] += av.x * wa[0] + av.y * wa[1] + av.z * wa[2] + av.w * wa[3]
                      + xv.x * wx[0] + xv.y * wx[1] + xv.z * wx[2] + xv.w * wx[3];
            }
        }
    } else {
        const int offA = half * HH;
        const int offB = HH - offA;
#pragma unroll 4
        for (int kb = 0; kb < HH; kb += 4) {
            float w1[4], w2[4], wx[4];
#pragma unroll
            for (int kk = 0; kk < 4; ++kk) {
                w1[kk] = Wa[(kb + kk) * HH + j];
                w2[kk] = Wa[(HH + kb + kk) * HH + j];
                wx[kk] = Wx[(kb + kk) * HH + j];
            }
#pragma unroll
            for (int m = 0; m < 4; ++m) {
                const int nm = g * 4 + m;
                const float4 a0 = *(const float4*)&agg[0][nm][offA + kb];
                const float4 a1 = *(const float4*)&agg[1][nm][offB + kb];
                const float4 xv = *(const float4*)&xr[nm][offA + kb];
                o[m] += a0.x * w1[0] + a0.y * w1[1] + a0.z * w1[2] + a0.w * w1[3]
                      + a1.x * w2[0] + a1.y * w2[1] + a1.z * w2[2] + a1.w * w2[3]
                      + xv.x * wx[0] + xv.y * wx[1] + xv.z * wx[2] + xv.w * wx[3];
            }
        }
    }

#pragma unroll
    for (int m = 0; m < 4; ++m) {
        const int node = base + g * 4 + m;
        if (node < nN) out[(size_t)node * CH + half * HH + j] = fast_tanh(o[m]);
    }
}

// ---------------- launch ----------------
extern "C" void kernel_launch(void* const* d_in, const int* in_sizes, int n_in,
                              void* d_out, int out_size, void* d_ws, size_t ws_size,
                              hipStream_t stream) {
    const float* x      = (const float*)d_in[0];
    const int*   pe     = (const int*)d_in[1];  // [2][E] src,dst
    const int*   ne     = (const int*)d_in[2];
    const float* Wp_l   = (const float*)d_in[3];
    const float* Wp_r   = (const float*)d_in[4];
    const float* bp     = (const float*)d_in[5];
    const float* Wn_l   = (const float*)d_in[6];
    const float* Wn_r   = (const float*)d_in[7];
    const float* bn     = (const float*)d_in[8];
    const float* Wl_pos = (const float*)d_in[9];
    const float* Wr_pos = (const float*)d_in[10];
    const float* b_pos  = (const float*)d_in[11];
    const float* Wl_neg = (const float*)d_in[12];
    const float* Wr_neg = (const float*)d_in[13];
    const float* b_neg  = (const float*)d_in[14];

    const int E = in_sizes[1] / 2;
    const int n = in_sizes[0] / CH;

    // workspace layout
    float* z0       = (float*)d_ws;                  // n*CH
    int*   cnt_p    = (int*)(z0 + (size_t)n * CH);   // n   (cnt_n follows: +n)
    int*   cnt_n    = cnt_p + n;
    int*   row_p    = cnt_n + n;                     // n+1 (row_n follows)
    int*   row_n    = row_p + n + 1;
    int*   cur_p    = row_n + n + 1;                 // n   (cur_n follows)
    int*   cur_n    = cur_p + n;
    int*   csr_p    = cur_n + n;                     // E
    int*   csr_n    = csr_p + E;                     // E
    int*   partials = csr_n + E;                     // 512

    hipMemsetAsync(cnt_p, 0, (size_t)2 * n * sizeof(int), stream);

    const int eb = 256, eg2 = (2 * E + eb - 1) / eb;
    const int nb = (n + SCAN_CHUNK - 1) / SCAN_CHUNK;  // <=256 for n<=262144

    count_kernel<<<eg2, eb, 0, stream>>>(pe + E, ne + E, cnt_p, cnt_n, E);
    partial_kernel<<<dim3(nb, 2), SCAN_T, 0, stream>>>(cnt_p, n, partials);
    scan_partials_kernel<<<dim3(1, 2), 256, 0, stream>>>(partials, nb);
    scan_apply_kernel<<<dim3(nb, 2), SCAN_T, 0, stream>>>(cnt_p, n, partials, row_p, cur_p, E);
    fill_kernel<<<eg2, eb, 0, stream>>>(pe, ne, cur_p, cur_n, csr_p, csr_n, E);

    float* zout = (float*)d_out;
    dim3 grid((n + 7) / 8);
    dim3 block(256);

    // Layer 0: x -> d_out
    layer_kernel<true><<<grid, block, 0, stream>>>(
        x, zout, row_p, csr_p, row_n, csr_n, Wp_l, Wp_r, bp, Wn_l, Wn_r, bn, n);
    // Layer 1: d_out -> z0
    layer_kernel<false><<<grid, block, 0, stream>>>(
        zout, z0, row_p, csr_p, row_n, csr_n,
        Wl_pos, Wr_pos, b_pos, Wl_neg, Wr_neg, b_neg, n);
    // Layer 2: z0 -> d_out
    layer_kernel<false><<<grid, block, 0, stream>>>(
        z0, zout, row_p, csr_p, row_n, csr_n,
        Wl_pos + CH * HH, Wr_pos + HH * HH, b_pos + HH,
        Wl_neg + CH * HH, Wr_neg + HH * HH, b_neg + HH, n);
}

// Round 3
// 1100.759 us; speedup vs baseline: 1.5377x; 1.4277x over previous
//
#include <hip/hip_runtime.h>
#include <math.h>

#define CH 128
#define HH 64
#define SCAN_T 256
#define SCAN_I 4
#define SCAN_CHUNK (SCAN_T * SCAN_I)

// ---------------- CSR build ----------------
__global__ void count_kernel(const int* __restrict__ pd, const int* __restrict__ nd,
                             int* __restrict__ cnt_p, int* __restrict__ cnt_n, int E) {
    int i = blockIdx.x * blockDim.x + threadIdx.x;
    if (i < E) atomicAdd(&cnt_p[pd[i]], 1);
    else if (i < 2 * E) atomicAdd(&cnt_n[nd[i - E]], 1);
}

__global__ void fill_kernel(const int* __restrict__ pe, const int* __restrict__ ne,
                            int* __restrict__ cur_p, int* __restrict__ cur_n,
                            int* __restrict__ csr_p, int* __restrict__ csr_n, int E) {
    int i = blockIdx.x * blockDim.x + threadIdx.x;
    if (i < E) {
        int p = atomicAdd(&cur_p[pe[E + i]], 1);
        csr_p[p] = pe[i];
    } else if (i < 2 * E) {
        int k = i - E;
        int p = atomicAdd(&cur_n[ne[E + k]], 1);
        csr_n[p] = ne[k];
    }
}

__global__ __launch_bounds__(SCAN_T) void partial_kernel(const int* __restrict__ cnt, int n,
                                                         int* __restrict__ partials) {
    const int y = blockIdx.y, b = blockIdx.x, t = threadIdx.x;
    const int* c = cnt + (size_t)y * n;
    const int base = b * SCAN_CHUNK + t * SCAN_I;
    int s = 0;
    if (base + SCAN_I <= n) {
        int4 v = *(const int4*)(c + base);
        s = v.x + v.y + v.z + v.w;
    } else {
        for (int i = 0; i < SCAN_I; ++i)
            if (base + i < n) s += c[base + i];
    }
    __shared__ int red[SCAN_T];
    red[t] = s;
    __syncthreads();
    for (int off = SCAN_T / 2; off > 0; off >>= 1) {
        if (t < off) red[t] += red[t + off];
        __syncthreads();
    }
    if (t == 0) partials[y * 256 + b] = red[0];
}

__global__ __launch_bounds__(256) void scan_partials_kernel(int* __restrict__ partials, int nb) {
    const int y = blockIdx.y, t = threadIdx.x;
    int* p = partials + y * 256;
    __shared__ int sh[256];
    sh[t] = (t < nb) ? p[t] : 0;
    __syncthreads();
    for (int off = 1; off < 256; off <<= 1) {
        int v = (t >= off) ? sh[t - off] : 0;
        __syncthreads();
        sh[t] += v;
        __syncthreads();
    }
    if (t < nb) p[t] = (t == 0) ? 0 : sh[t - 1];
}

__global__ __launch_bounds__(SCAN_T) void scan_apply_kernel(const int* __restrict__ cnt, int n,
                                                            const int* __restrict__ partials,
                                                            int* __restrict__ row,
                                                            int* __restrict__ cur, int total) {
    const int y = blockIdx.y, b = blockIdx.x, t = threadIdx.x;
    const int* c = cnt + (size_t)y * n;
    int* r = row + (size_t)y * (n + 1);
    int* q = cur + (size_t)y * n;
    const int base = b * SCAN_CHUNK + t * SCAN_I;
    int v0 = 0, v1 = 0, v2 = 0, v3 = 0;
    const bool full = (base + SCAN_I <= n);
    if (full) {
        int4 vv = *(const int4*)(c + base);
        v0 = vv.x; v1 = vv.y; v2 = vv.z; v3 = vv.w;
    } else {
        if (base + 0 < n) v0 = c[base + 0];
        if (base + 1 < n) v1 = c[base + 1];
        if (base + 2 < n) v2 = c[base + 2];
        if (base + 3 < n) v3 = c[base + 3];
    }
    const int s = v0 + v1 + v2 + v3;
    __shared__ int sh[SCAN_T];
    sh[t] = s;
    __syncthreads();
    for (int off = 1; off < SCAN_T; off <<= 1) {
        int v = (t >= off) ? sh[t - off] : 0;
        __syncthreads();
        sh[t] += v;
        __syncthreads();
    }
    int run = partials[y * 256 + b] + sh[t] - s;
    if (full) {
        int4 rv;
        rv.x = run; rv.y = run + v0; rv.z = run + v0 + v1; rv.w = run + v0 + v1 + v2;
        *(int4*)(r + base) = rv;
        *(int4*)(q + base) = rv;
    } else {
        if (base + 0 < n) { r[base + 0] = run; q[base + 0] = run; run += v0; }
        if (base + 1 < n) { r[base + 1] = run; q[base + 1] = run; run += v1; }
        if (base + 2 < n) { r[base + 2] = run; q[base + 2] = run; run += v2; }
        if (base + 3 < n) { r[base + 3] = run; q[base + 3] = run; run += v3; }
    }
    if (b == 0 && t == 0) r[n] = total;
}

// ---------------- fused layer ----------------
__device__ __forceinline__ float fast_tanh(float x) {
    float e = __expf(2.0f * x);
    return 1.0f - 2.0f * __builtin_amdgcn_rcpf(e + 1.0f);
}

// Block = 256 = 4 waves, 8 nodes.
// Phase 1: wave-uniform node (readfirstlane) -> csr/row reads become scalar
//          loads, per-edge row address on the scalar unit; lane covers 2 ch
//          (float2). Edge loop unrolled x4: 4 independent 512B row fetches
//          in flight per wave.
// Phase 2: wave -> (4-node group, col half); lane j = out col; scalar-k loop
//          (low VGPR; LDS uniform-address broadcast reads).
template <bool L0>
__global__ __launch_bounds__(256) void layer_kernel(
    const float* __restrict__ feat, float* __restrict__ out,
    const int* __restrict__ row_p, const int* __restrict__ csr_p,
    const int* __restrict__ row_n, const int* __restrict__ csr_n,
    const float* __restrict__ W0, const float* __restrict__ W1, const float* __restrict__ b0,
    const float* __restrict__ W2, const float* __restrict__ W3, const float* __restrict__ b1,
    int nN) {
    __shared__ __align__(16) float agg[2][8][CH];
    __shared__ __align__(16) float xr[8][CH];

    const int t = threadIdx.x;
    const int wave = __builtin_amdgcn_readfirstlane(t >> 6);  // wave-uniform
    const int lane = t & 63;
    const int base = blockIdx.x * 8;

    // ---- Phase 1: aggregation ----
#pragma unroll
    for (int i = 0; i < 2; ++i) {
        const int m = wave * 2 + i;          // uniform
        const int node = base + m;           // uniform
        if (node < nN) {
            float2 xv = ((const float2*)(feat + (size_t)node * CH))[lane];
            ((float2*)&xr[m][0])[lane] = xv;
#pragma unroll
            for (int s = 0; s < 2; ++s) {
                const int* __restrict__ rowp = s ? row_n : row_p;
                const int* __restrict__ csr = s ? csr_n : csr_p;
                const int s0 = rowp[node], s1 = rowp[node + 1];  // scalar loads
                float ax = 0.f, ay = 0.f;
                int e = s0;
                for (; e + 3 < s1; e += 4) {
                    const int a0 = csr[e], a1 = csr[e + 1], a2 = csr[e + 2], a3 = csr[e + 3];
                    const float2 v0 = ((const float2*)(feat + (size_t)a0 * CH))[lane];
                    const float2 v1 = ((const float2*)(feat + (size_t)a1 * CH))[lane];
                    const float2 v2 = ((const float2*)(feat + (size_t)a2 * CH))[lane];
                    const float2 v3 = ((const float2*)(feat + (size_t)a3 * CH))[lane];
                    ax += (v0.x + v1.x) + (v2.x + v3.x);
                    ay += (v0.y + v1.y) + (v2.y + v3.y);
                }
                for (; e < s1; ++e) {
                    const int a0 = csr[e];
                    const float2 v0 = ((const float2*)(feat + (size_t)a0 * CH))[lane];
                    ax += v0.x;
                    ay += v0.y;
                }
                const int d = s1 - s0;
                const float inv = 1.0f / (float)(d > 1 ? d : 1);
                ((float2*)&agg[s][m][0])[lane] = make_float2(ax * inv, ay * inv);
            }
        }
    }
    __syncthreads();

    // ---- Phase 2: matmul + tanh ----
    const int g = wave >> 1;
    const int half = wave & 1;
    const int j = lane;
    const float* __restrict__ Wa = half ? W2 : W0;
    const float* __restrict__ Wx = half ? W3 : W1;
    const float* __restrict__ bb = half ? b1 : b0;

    float o[4];
    const float bj = bb[j];
#pragma unroll
    for (int m = 0; m < 4; ++m) o[m] = bj;

    if (L0) {
#pragma unroll 4
        for (int k = 0; k < CH; ++k) {
            float wa = Wa[k * HH + j];
            float wx = Wx[k * HH + j];
#pragma unroll
            for (int m = 0; m < 4; ++m) {
                const int nm = g * 4 + m;
                o[m] += agg[half][nm][k] * wa + xr[nm][k] * wx;
            }
        }
    } else {
        const int offA = half * HH;
        const int offB = HH - offA;
#pragma unroll 4
        for (int k = 0; k < HH; ++k) {
            float w1 = Wa[k * HH + j];
            float w2 = Wa[(HH + k) * HH + j];
            float wx = Wx[k * HH + j];
#pragma unroll
            for (int m = 0; m < 4; ++m) {
                const int nm = g * 4 + m;
                o[m] += agg[0][nm][offA + k] * w1 + agg[1][nm][offB + k] * w2 +
                        xr[nm][offA + k] * wx;
            }
        }
    }

#pragma unroll
    for (int m = 0; m < 4; ++m) {
        const int node = base + g * 4 + m;
        if (node < nN) out[(size_t)node * CH + half * HH + j] = fast_tanh(o[m]);
    }
}

// ---------------- launch ----------------
extern "C" void kernel_launch(void* const* d_in, const int* in_sizes, int n_in,
                              void* d_out, int out_size, void* d_ws, size_t ws_size,
                              hipStream_t stream) {
    const float* x      = (const float*)d_in[0];
    const int*   pe     = (const int*)d_in[1];  // [2][E] src,dst
    const int*   ne     = (const int*)d_in[2];
    const float* Wp_l   = (const float*)d_in[3];
    const float* Wp_r   = (const float*)d_in[4];
    const float* bp     = (const float*)d_in[5];
    const float* Wn_l   = (const float*)d_in[6];
    const float* Wn_r   = (const float*)d_in[7];
    const float* bn     = (const float*)d_in[8];
    const float* Wl_pos = (const float*)d_in[9];
    const float* Wr_pos = (const float*)d_in[10];
    const float* b_pos  = (const float*)d_in[11];
    const float* Wl_neg = (const float*)d_in[12];
    const float* Wr_neg = (const float*)d_in[13];
    const float* b_neg  = (const float*)d_in[14];

    const int E = in_sizes[1] / 2;
    const int n = in_sizes[0] / CH;

    float* z0       = (float*)d_ws;                  // n*CH
    int*   cnt_p    = (int*)(z0 + (size_t)n * CH);   // n (+cnt_n n)
    int*   cnt_n    = cnt_p + n;
    int*   row_p    = cnt_n + n;                     // n+1 (+row_n)
    int*   row_n    = row_p + n + 1;
    int*   cur_p    = row_n + n + 1;                 // n (+cur_n)
    int*   cur_n    = cur_p + n;
    int*   csr_p    = cur_n + n;                     // E
    int*   csr_n    = csr_p + E;                     // E
    int*   partials = csr_n + E;                     // 512

    hipMemsetAsync(cnt_p, 0, (size_t)2 * n * sizeof(int), stream);

    const int eb = 256, eg2 = (2 * E + eb - 1) / eb;
    const int nb = (n + SCAN_CHUNK - 1) / SCAN_CHUNK;

    count_kernel<<<eg2, eb, 0, stream>>>(pe + E, ne + E, cnt_p, cnt_n, E);
    partial_kernel<<<dim3(nb, 2), SCAN_T, 0, stream>>>(cnt_p, n, partials);
    scan_partials_kernel<<<dim3(1, 2), 256, 0, stream>>>(partials, nb);
    scan_apply_kernel<<<dim3(nb, 2), SCAN_T, 0, stream>>>(cnt_p, n, partials, row_p, cur_p, E);
    fill_kernel<<<eg2, eb, 0, stream>>>(pe, ne, cur_p, cur_n, csr_p, csr_n, E);

    float* zout = (float*)d_out;
    dim3 grid((n + 7) / 8);
    dim3 block(256);

    layer_kernel<true><<<grid, block, 0, stream>>>(
        x, zout, row_p, csr_p, row_n, csr_n, Wp_l, Wp_r, bp, Wn_l, Wn_r, bn, n);
    layer_kernel<false><<<grid, block, 0, stream>>>(
        zout, z0, row_p, csr_p, row_n, csr_n,
        Wl_pos, Wr_pos, b_pos, Wl_neg, Wr_neg, b_neg, n);
    layer_kernel<false><<<grid, block, 0, stream>>>(
        z0, zout, row_p, csr_p, row_n, csr_n,
        Wl_pos + CH * HH, Wr_pos + HH * HH, b_pos + HH,
        Wl_neg + CH * HH, Wr_neg + HH * HH, b_neg + HH, n);
}

// Round 4
// 1017.011 us; speedup vs baseline: 1.6643x; 1.0823x over previous
//
#include <hip/hip_runtime.h>
#include <math.h>

#define CH 128
#define HH 64
#define SCAN_T 256
#define SCAN_I 4
#define SCAN_CHUNK (SCAN_T * SCAN_I)

// ---------------- CSR build ----------------
__global__ void count_kernel(const int* __restrict__ pd, const int* __restrict__ nd,
                             int* __restrict__ cnt_p, int* __restrict__ cnt_n, int E) {
    int i = blockIdx.x * blockDim.x + threadIdx.x;
    if (i < E) atomicAdd(&cnt_p[pd[i]], 1);
    else if (i < 2 * E) atomicAdd(&cnt_n[nd[i - E]], 1);
}

__global__ void fill_kernel(const int* __restrict__ pe, const int* __restrict__ ne,
                            int* __restrict__ cur_p, int* __restrict__ cur_n,
                            int* __restrict__ csr_p, int* __restrict__ csr_n, int E) {
    int i = blockIdx.x * blockDim.x + threadIdx.x;
    if (i < E) {
        int p = atomicAdd(&cur_p[pe[E + i]], 1);
        csr_p[p] = pe[i];
    } else if (i < 2 * E) {
        int k = i - E;
        int p = atomicAdd(&cur_n[ne[E + k]], 1);
        csr_n[p] = ne[k];
    }
}

__global__ __launch_bounds__(SCAN_T) void partial_kernel(const int* __restrict__ cnt, int n,
                                                         int* __restrict__ partials) {
    const int y = blockIdx.y, b = blockIdx.x, t = threadIdx.x;
    const int* c = cnt + (size_t)y * n;
    const int base = b * SCAN_CHUNK + t * SCAN_I;
    int s = 0;
    if (base + SCAN_I <= n) {
        int4 v = *(const int4*)(c + base);
        s = v.x + v.y + v.z + v.w;
    } else {
        for (int i = 0; i < SCAN_I; ++i)
            if (base + i < n) s += c[base + i];
    }
    __shared__ int red[SCAN_T];
    red[t] = s;
    __syncthreads();
    for (int off = SCAN_T / 2; off > 0; off >>= 1) {
        if (t < off) red[t] += red[t + off];
        __syncthreads();
    }
    if (t == 0) partials[y * 256 + b] = red[0];
}

__global__ __launch_bounds__(256) void scan_partials_kernel(int* __restrict__ partials, int nb) {
    const int y = blockIdx.y, t = threadIdx.x;
    int* p = partials + y * 256;
    __shared__ int sh[256];
    sh[t] = (t < nb) ? p[t] : 0;
    __syncthreads();
    for (int off = 1; off < 256; off <<= 1) {
        int v = (t >= off) ? sh[t - off] : 0;
        __syncthreads();
        sh[t] += v;
        __syncthreads();
    }
    if (t < nb) p[t] = (t == 0) ? 0 : sh[t - 1];
}

__global__ __launch_bounds__(SCAN_T) void scan_apply_kernel(const int* __restrict__ cnt, int n,
                                                            const int* __restrict__ partials,
                                                            int* __restrict__ row,
                                                            int* __restrict__ cur, int total) {
    const int y = blockIdx.y, b = blockIdx.x, t = threadIdx.x;
    const int* c = cnt + (size_t)y * n;
    int* r = row + (size_t)y * (n + 1);
    int* q = cur + (size_t)y * n;
    const int base = b * SCAN_CHUNK + t * SCAN_I;
    int v0 = 0, v1 = 0, v2 = 0, v3 = 0;
    const bool full = (base + SCAN_I <= n);
    if (full) {
        int4 vv = *(const int4*)(c + base);
        v0 = vv.x; v1 = vv.y; v2 = vv.z; v3 = vv.w;
    } else {
        if (base + 0 < n) v0 = c[base + 0];
        if (base + 1 < n) v1 = c[base + 1];
        if (base + 2 < n) v2 = c[base + 2];
        if (base + 3 < n) v3 = c[base + 3];
    }
    const int s = v0 + v1 + v2 + v3;
    __shared__ int sh[SCAN_T];
    sh[t] = s;
    __syncthreads();
    for (int off = 1; off < SCAN_T; off <<= 1) {
        int v = (t >= off) ? sh[t - off] : 0;
        __syncthreads();
        sh[t] += v;
        __syncthreads();
    }
    int run = partials[y * 256 + b] + sh[t] - s;
    if (full) {
        int4 rv;
        rv.x = run; rv.y = run + v0; rv.z = run + v0 + v1; rv.w = run + v0 + v1 + v2;
        *(int4*)(r + base) = rv;
        *(int4*)(q + base) = rv;
    } else {
        if (base + 0 < n) { r[base + 0] = run; q[base + 0] = run; run += v0; }
        if (base + 1 < n) { r[base + 1] = run; q[base + 1] = run; run += v1; }
        if (base + 2 < n) { r[base + 2] = run; q[base + 2] = run; run += v2; }
        if (base + 3 < n) { r[base + 3] = run; q[base + 3] = run; run += v3; }
    }
    if (b == 0 && t == 0) r[n] = total;
}

// ---------------- helpers ----------------
__device__ __forceinline__ float fast_tanh(float x) {
    float e = __expf(2.0f * x);
    return 1.0f - 2.0f * __builtin_amdgcn_rcpf(e + 1.0f);
}

__device__ __forceinline__ unsigned short f2bf(float f) {  // RNE
    unsigned u = __float_as_uint(f);
    u += 0x7fffu + ((u >> 16) & 1u);
    return (unsigned short)(u >> 16);
}

__device__ __forceinline__ float bf_lo(unsigned v) { return __uint_as_float(v << 16); }
__device__ __forceinline__ float bf_hi(unsigned v) { return __uint_as_float(v & 0xffff0000u); }

// fp32 x -> bf16 copy (row-major, 4 elems/thread)
__global__ __launch_bounds__(256) void conv_kernel(const float* __restrict__ x,
                                                   unsigned short* __restrict__ xb, int total4) {
    int i = blockIdx.x * blockDim.x + threadIdx.x;
    if (i < total4) {
        float4 v = ((const float4*)x)[i];
        ushort4 o;
        o.x = f2bf(v.x); o.y = f2bf(v.y); o.z = f2bf(v.z); o.w = f2bf(v.w);
        ((ushort4*)xb)[i] = o;
    }
}

// ---------------- fused layer ----------------
// Block = 256 = 4 waves, 8 nodes. Features are bf16 (256 B/row).
// Phase 1: wave-uniform node; csr/row via scalar loads; lane loads one dword
//          (2 packed bf16 ch) per edge row; unroll x4 for MLP; unpack via
//          shift/and; fp32 accumulate; agg stays fp32 in LDS.
// Phase 2: unchanged fp32 matmul + tanh; output bf16 (L0/L1) or fp32 (L2).
template <bool L0, bool OBF>
__global__ __launch_bounds__(256) void layer_kernel(
    const unsigned short* __restrict__ feat, void* __restrict__ outv,
    const int* __restrict__ row_p, const int* __restrict__ csr_p,
    const int* __restrict__ row_n, const int* __restrict__ csr_n,
    const float* __restrict__ W0, const float* __restrict__ W1, const float* __restrict__ b0,
    const float* __restrict__ W2, const float* __restrict__ W3, const float* __restrict__ b1,
    int nN) {
    __shared__ __align__(16) float agg[2][8][CH];
    __shared__ __align__(16) float xr[8][CH];

    const int t = threadIdx.x;
    const int wave = __builtin_amdgcn_readfirstlane(t >> 6);
    const int lane = t & 63;
    const int base = blockIdx.x * 8;

    // ---- Phase 1 ----
#pragma unroll
    for (int i = 0; i < 2; ++i) {
        const int m = wave * 2 + i;   // uniform
        const int node = base + m;    // uniform
        if (node < nN) {
            {
                const unsigned v = ((const unsigned*)(feat + (size_t)node * CH))[lane];
                ((float2*)&xr[m][0])[lane] = make_float2(bf_lo(v), bf_hi(v));
            }
#pragma unroll
            for (int s = 0; s < 2; ++s) {
                const int* __restrict__ rowp = s ? row_n : row_p;
                const int* __restrict__ csr = s ? csr_n : csr_p;
                const int s0 = rowp[node], s1 = rowp[node + 1];
                float ax = 0.f, ay = 0.f;
                int e = s0;
                for (; e + 3 < s1; e += 4) {
                    const int a0 = csr[e], a1 = csr[e + 1], a2 = csr[e + 2], a3 = csr[e + 3];
                    const unsigned v0 = ((const unsigned*)(feat + (size_t)a0 * CH))[lane];
                    const unsigned v1 = ((const unsigned*)(feat + (size_t)a1 * CH))[lane];
                    const unsigned v2 = ((const unsigned*)(feat + (size_t)a2 * CH))[lane];
                    const unsigned v3 = ((const unsigned*)(feat + (size_t)a3 * CH))[lane];
                    ax += (bf_lo(v0) + bf_lo(v1)) + (bf_lo(v2) + bf_lo(v3));
                    ay += (bf_hi(v0) + bf_hi(v1)) + (bf_hi(v2) + bf_hi(v3));
                }
                for (; e < s1; ++e) {
                    const unsigned v0 = ((const unsigned*)(feat + (size_t)csr[e] * CH))[lane];
                    ax += bf_lo(v0);
                    ay += bf_hi(v0);
                }
                const int d = s1 - s0;
                const float inv = 1.0f / (float)(d > 1 ? d : 1);
                ((float2*)&agg[s][m][0])[lane] = make_float2(ax * inv, ay * inv);
            }
        }
    }
    __syncthreads();

    // ---- Phase 2 ----
    const int g = wave >> 1;
    const int half = wave & 1;
    const int j = lane;
    const float* __restrict__ Wa = half ? W2 : W0;
    const float* __restrict__ Wx = half ? W3 : W1;
    const float* __restrict__ bb = half ? b1 : b0;

    float o[4];
    const float bj = bb[j];
#pragma unroll
    for (int m = 0; m < 4; ++m) o[m] = bj;

    if (L0) {
#pragma unroll 4
        for (int k = 0; k < CH; ++k) {
            float wa = Wa[k * HH + j];
            float wx = Wx[k * HH + j];
#pragma unroll
            for (int m = 0; m < 4; ++m) {
                const int nm = g * 4 + m;
                o[m] += agg[half][nm][k] * wa + xr[nm][k] * wx;
            }
        }
    } else {
        const int offA = half * HH;
        const int offB = HH - offA;
#pragma unroll 4
        for (int k = 0; k < HH; ++k) {
            float w1 = Wa[k * HH + j];
            float w2 = Wa[(HH + k) * HH + j];
            float wx = Wx[k * HH + j];
#pragma unroll
            for (int m = 0; m < 4; ++m) {
                const int nm = g * 4 + m;
                o[m] += agg[0][nm][offA + k] * w1 + agg[1][nm][offB + k] * w2 +
                        xr[nm][offA + k] * wx;
            }
        }
    }

#pragma unroll
    for (int m = 0; m < 4; ++m) {
        const int node = base + g * 4 + m;
        if (node < nN) {
            const float r = fast_tanh(o[m]);
            if (OBF)
                ((unsigned short*)outv)[(size_t)node * CH + half * HH + j] = f2bf(r);
            else
                ((float*)outv)[(size_t)node * CH + half * HH + j] = r;
        }
    }
}

// ---------------- launch ----------------
extern "C" void kernel_launch(void* const* d_in, const int* in_sizes, int n_in,
                              void* d_out, int out_size, void* d_ws, size_t ws_size,
                              hipStream_t stream) {
    const float* x      = (const float*)d_in[0];
    const int*   pe     = (const int*)d_in[1];  // [2][E] src,dst
    const int*   ne     = (const int*)d_in[2];
    const float* Wp_l   = (const float*)d_in[3];
    const float* Wp_r   = (const float*)d_in[4];
    const float* bp     = (const float*)d_in[5];
    const float* Wn_l   = (const float*)d_in[6];
    const float* Wn_r   = (const float*)d_in[7];
    const float* bn     = (const float*)d_in[8];
    const float* Wl_pos = (const float*)d_in[9];
    const float* Wr_pos = (const float*)d_in[10];
    const float* b_pos  = (const float*)d_in[11];
    const float* Wl_neg = (const float*)d_in[12];
    const float* Wr_neg = (const float*)d_in[13];
    const float* b_neg  = (const float*)d_in[14];

    const int E = in_sizes[1] / 2;
    const int n = in_sizes[0] / CH;

    // workspace layout (16B-aligned chunks)
    unsigned short* xb  = (unsigned short*)d_ws;        // n*CH bf16 (reused as zB)
    unsigned short* zA  = xb + (size_t)n * CH;          // n*CH bf16
    int* cnt_p    = (int*)(zA + (size_t)n * CH);        // n
    int* cnt_n    = cnt_p + n;
    int* row_p    = cnt_n + n;                          // n+1
    int* row_n    = row_p + n + 1;
    int* cur_p    = row_n + n + 1;                      // n
    int* cur_n    = cur_p + n;
    int* csr_p    = cur_n + n;                          // E
    int* csr_n    = csr_p + E;                          // E
    int* partials = csr_n + E;                          // 512

    hipMemsetAsync(cnt_p, 0, (size_t)2 * n * sizeof(int), stream);

    const int eb = 256, eg2 = (2 * E + eb - 1) / eb;
    const int nb = (n + SCAN_CHUNK - 1) / SCAN_CHUNK;

    const int total4 = n * CH / 4;
    conv_kernel<<<(total4 + 255) / 256, 256, 0, stream>>>(x, xb, total4);

    count_kernel<<<eg2, eb, 0, stream>>>(pe + E, ne + E, cnt_p, cnt_n, E);
    partial_kernel<<<dim3(nb, 2), SCAN_T, 0, stream>>>(cnt_p, n, partials);
    scan_partials_kernel<<<dim3(1, 2), 256, 0, stream>>>(partials, nb);
    scan_apply_kernel<<<dim3(nb, 2), SCAN_T, 0, stream>>>(cnt_p, n, partials, row_p, cur_p, E);
    fill_kernel<<<eg2, eb, 0, stream>>>(pe, ne, cur_p, cur_n, csr_p, csr_n, E);

    dim3 grid((n + 7) / 8);
    dim3 block(256);

    // L0: xb -> zA (bf16)
    layer_kernel<true, true><<<grid, block, 0, stream>>>(
        xb, zA, row_p, csr_p, row_n, csr_n, Wp_l, Wp_r, bp, Wn_l, Wn_r, bn, n);
    // L1: zA -> xb (bf16, reuse)
    layer_kernel<false, true><<<grid, block, 0, stream>>>(
        zA, xb, row_p, csr_p, row_n, csr_n,
        Wl_pos, Wr_pos, b_pos, Wl_neg, Wr_neg, b_neg, n);
    // L2: xb -> d_out (fp32)
    layer_kernel<false, false><<<grid, block, 0, stream>>>(
        xb, d_out, row_p, csr_p, row_n, csr_n,
        Wl_pos + CH * HH, Wr_pos + HH * HH, b_pos + HH,
        Wl_neg + CH * HH, Wr_neg + HH * HH, b_neg + HH, n);
}

// Round 5
// 848.111 us; speedup vs baseline: 1.9958x; 1.1991x over previous
//
#include <hip/hip_runtime.h>
#include <math.h>

#define CH 128
#define SCAN_T 256
#define SCAN_I 4
#define SCAN_CHUNK (SCAN_T * SCAN_I)

typedef __attribute__((ext_vector_type(8))) short bf16x8;
typedef __attribute__((ext_vector_type(4))) float f32x4;

// ---------------- CSR build ----------------
__global__ void count_kernel(const int* __restrict__ pd, const int* __restrict__ nd,
                             int* __restrict__ cnt_p, int* __restrict__ cnt_n, int E) {
    int i = blockIdx.x * blockDim.x + threadIdx.x;
    if (i < E) atomicAdd(&cnt_p[pd[i]], 1);
    else if (i < 2 * E) atomicAdd(&cnt_n[nd[i - E]], 1);
}

__global__ void fill_kernel(const int* __restrict__ pe, const int* __restrict__ ne,
                            int* __restrict__ cur_p, int* __restrict__ cur_n,
                            int* __restrict__ csr_p, int* __restrict__ csr_n, int E) {
    int i = blockIdx.x * blockDim.x + threadIdx.x;
    if (i < E) {
        int p = atomicAdd(&cur_p[pe[E + i]], 1);
        csr_p[p] = pe[i];
    } else if (i < 2 * E) {
        int k = i - E;
        int p = atomicAdd(&cur_n[ne[E + k]], 1);
        csr_n[p] = ne[k];
    }
}

__global__ __launch_bounds__(SCAN_T) void partial_kernel(const int* __restrict__ cnt, int n,
                                                         int* __restrict__ partials) {
    const int y = blockIdx.y, b = blockIdx.x, t = threadIdx.x;
    const int* c = cnt + (size_t)y * n;
    const int base = b * SCAN_CHUNK + t * SCAN_I;
    int s = 0;
    if (base + SCAN_I <= n) {
        int4 v = *(const int4*)(c + base);
        s = v.x + v.y + v.z + v.w;
    } else {
        for (int i = 0; i < SCAN_I; ++i)
            if (base + i < n) s += c[base + i];
    }
    __shared__ int red[SCAN_T];
    red[t] = s;
    __syncthreads();
    for (int off = SCAN_T / 2; off > 0; off >>= 1) {
        if (t < off) red[t] += red[t + off];
        __syncthreads();
    }
    if (t == 0) partials[y * 256 + b] = red[0];
}

__global__ __launch_bounds__(256) void scan_partials_kernel(int* __restrict__ partials, int nb) {
    const int y = blockIdx.y, t = threadIdx.x;
    int* p = partials + y * 256;
    __shared__ int sh[256];
    sh[t] = (t < nb) ? p[t] : 0;
    __syncthreads();
    for (int off = 1; off < 256; off <<= 1) {
        int v = (t >= off) ? sh[t - off] : 0;
        __syncthreads();
        sh[t] += v;
        __syncthreads();
    }
    if (t < nb) p[t] = (t == 0) ? 0 : sh[t - 1];
}

__global__ __launch_bounds__(SCAN_T) void scan_apply_kernel(const int* __restrict__ cnt, int n,
                                                            const int* __restrict__ partials,
                                                            int* __restrict__ row,
                                                            int* __restrict__ cur, int total) {
    const int y = blockIdx.y, b = blockIdx.x, t = threadIdx.x;
    const int* c = cnt + (size_t)y * n;
    int* r = row + (size_t)y * (n + 1);
    int* q = cur + (size_t)y * n;
    const int base = b * SCAN_CHUNK + t * SCAN_I;
    int v0 = 0, v1 = 0, v2 = 0, v3 = 0;
    const bool full = (base + SCAN_I <= n);
    if (full) {
        int4 vv = *(const int4*)(c + base);
        v0 = vv.x; v1 = vv.y; v2 = vv.z; v3 = vv.w;
    } else {
        if (base + 0 < n) v0 = c[base + 0];
        if (base + 1 < n) v1 = c[base + 1];
        if (base + 2 < n) v2 = c[base + 2];
        if (base + 3 < n) v3 = c[base + 3];
    }
    const int s = v0 + v1 + v2 + v3;
    __shared__ int sh[SCAN_T];
    sh[t] = s;
    __syncthreads();
    for (int off = 1; off < SCAN_T; off <<= 1) {
        int v = (t >= off) ? sh[t - off] : 0;
        __syncthreads();
        sh[t] += v;
        __syncthreads();
    }
    int run = partials[y * 256 + b] + sh[t] - s;
    if (full) {
        int4 rv;
        rv.x = run; rv.y = run + v0; rv.z = run + v0 + v1; rv.w = run + v0 + v1 + v2;
        *(int4*)(r + base) = rv;
        *(int4*)(q + base) = rv;
    } else {
        if (base + 0 < n) { r[base + 0] = run; q[base + 0] = run; run += v0; }
        if (base + 1 < n) { r[base + 1] = run; q[base + 1] = run; run += v1; }
        if (base + 2 < n) { r[base + 2] = run; q[base + 2] = run; run += v2; }
        if (base + 3 < n) { r[base + 3] = run; q[base + 3] = run; run += v3; }
    }
    if (b == 0 && t == 0) r[n] = total;
}

// ---------------- helpers ----------------
__device__ __forceinline__ float fast_tanh(float x) {
    float e = __expf(2.0f * x);
    return 1.0f - 2.0f * __builtin_amdgcn_rcpf(e + 1.0f);
}

__device__ __forceinline__ unsigned short f2bf(float f) {  // RNE
    unsigned u = __float_as_uint(f);
    u += 0x7fffu + ((u >> 16) & 1u);
    return (unsigned short)(u >> 16);
}

__device__ __forceinline__ float bf_lo(unsigned v) { return __uint_as_float(v << 16); }
__device__ __forceinline__ float bf_hi(unsigned v) { return __uint_as_float(v & 0xffff0000u); }

// ---------------- aggregate ----------------
// One wave per (node, sign). No LDS, low VGPR, edge loop unrolled x8.
// lane covers channels (2*lane, 2*lane+1); output packed bf16 dword.
template <bool FP32IN>
__global__ __launch_bounds__(256) void agg_kernel(
    const void* __restrict__ featv,
    unsigned* __restrict__ aggp, unsigned* __restrict__ aggn,
    const int* __restrict__ row_p, const int* __restrict__ csr_p,
    const int* __restrict__ row_n, const int* __restrict__ csr_n, int nN) {
    const int t = threadIdx.x;
    const int wave = __builtin_amdgcn_readfirstlane(t >> 6);
    const int lane = t & 63;
    const int node = blockIdx.x * 2 + (wave >> 1);
    const int sign = wave & 1;
    if (node >= nN) return;
    const int* __restrict__ rowp = sign ? row_n : row_p;
    const int* __restrict__ csr = sign ? csr_n : csr_p;
    unsigned* __restrict__ out = sign ? aggn : aggp;
    const int s0 = rowp[node], s1 = rowp[node + 1];
    float ax = 0.f, ay = 0.f;
    int e = s0;
    if (FP32IN) {
        const float* feat = (const float*)featv;
        for (; e + 7 < s1; e += 8) {
            const int a0 = csr[e], a1 = csr[e+1], a2 = csr[e+2], a3 = csr[e+3];
            const int a4 = csr[e+4], a5 = csr[e+5], a6 = csr[e+6], a7 = csr[e+7];
            const float2 v0 = ((const float2*)(feat + (size_t)a0 * CH))[lane];
            const float2 v1 = ((const float2*)(feat + (size_t)a1 * CH))[lane];
            const float2 v2 = ((const float2*)(feat + (size_t)a2 * CH))[lane];
            const float2 v3 = ((const float2*)(feat + (size_t)a3 * CH))[lane];
            const float2 v4 = ((const float2*)(feat + (size_t)a4 * CH))[lane];
            const float2 v5 = ((const float2*)(feat + (size_t)a5 * CH))[lane];
            const float2 v6 = ((const float2*)(feat + (size_t)a6 * CH))[lane];
            const float2 v7 = ((const float2*)(feat + (size_t)a7 * CH))[lane];
            ax += ((v0.x + v1.x) + (v2.x + v3.x)) + ((v4.x + v5.x) + (v6.x + v7.x));
            ay += ((v0.y + v1.y) + (v2.y + v3.y)) + ((v4.y + v5.y) + (v6.y + v7.y));
        }
        for (; e + 1 < s1; e += 2) {
            const int a0 = csr[e], a1 = csr[e + 1];
            const float2 v0 = ((const float2*)(feat + (size_t)a0 * CH))[lane];
            const float2 v1 = ((const float2*)(feat + (size_t)a1 * CH))[lane];
            ax += v0.x + v1.x;
            ay += v0.y + v1.y;
        }
        if (e < s1) {
            const float2 v0 = ((const float2*)(feat + (size_t)csr[e] * CH))[lane];
            ax += v0.x; ay += v0.y;
        }
    } else {
        const unsigned short* feat = (const unsigned short*)featv;
        for (; e + 7 < s1; e += 8) {
            const int a0 = csr[e], a1 = csr[e+1], a2 = csr[e+2], a3 = csr[e+3];
            const int a4 = csr[e+4], a5 = csr[e+5], a6 = csr[e+6], a7 = csr[e+7];
            const unsigned v0 = ((const unsigned*)(feat + (size_t)a0 * CH))[lane];
            const unsigned v1 = ((const unsigned*)(feat + (size_t)a1 * CH))[lane];
            const unsigned v2 = ((const unsigned*)(feat + (size_t)a2 * CH))[lane];
            const unsigned v3 = ((const unsigned*)(feat + (size_t)a3 * CH))[lane];
            const unsigned v4 = ((const unsigned*)(feat + (size_t)a4 * CH))[lane];
            const unsigned v5 = ((const unsigned*)(feat + (size_t)a5 * CH))[lane];
            const unsigned v6 = ((const unsigned*)(feat + (size_t)a6 * CH))[lane];
            const unsigned v7 = ((const unsigned*)(feat + (size_t)a7 * CH))[lane];
            ax += ((bf_lo(v0) + bf_lo(v1)) + (bf_lo(v2) + bf_lo(v3))) +
                  ((bf_lo(v4) + bf_lo(v5)) + (bf_lo(v6) + bf_lo(v7)));
            ay += ((bf_hi(v0) + bf_hi(v1)) + (bf_hi(v2) + bf_hi(v3))) +
                  ((bf_hi(v4) + bf_hi(v5)) + (bf_hi(v6) + bf_hi(v7)));
        }
        for (; e + 1 < s1; e += 2) {
            const unsigned v0 = ((const unsigned*)(feat + (size_t)csr[e] * CH))[lane];
            const unsigned v1 = ((const unsigned*)(feat + (size_t)csr[e + 1] * CH))[lane];
            ax += bf_lo(v0) + bf_lo(v1);
            ay += bf_hi(v0) + bf_hi(v1);
        }
        if (e < s1) {
            const unsigned v0 = ((const unsigned*)(feat + (size_t)csr[e] * CH))[lane];
            ax += bf_lo(v0); ay += bf_hi(v0);
        }
    }
    const int d = s1 - s0;
    const float inv = 1.0f / (float)(d > 1 ? d : 1);
    ax *= inv; ay *= inv;
    out[(size_t)node * 64 + lane] = (unsigned)f2bf(ax) | ((unsigned)f2bf(ay) << 16);
}

// ---------------- weight packing ----------------
// Wcat[384x128] per layer -> MFMA B-frag layout:
// packed[(L*12+ks)*8+nt][lane][j] = Wcat[ks*32+(lane>>4)*8+j][nt*16+(lane&15)]
__global__ __launch_bounds__(64) void wpack_kernel(
    const float* __restrict__ Wp_l, const float* __restrict__ Wp_r,
    const float* __restrict__ Wn_l, const float* __restrict__ Wn_r,
    const float* __restrict__ Wl_pos, const float* __restrict__ Wr_pos,
    const float* __restrict__ Wl_neg, const float* __restrict__ Wr_neg,
    unsigned short* __restrict__ Wpk) {
    const int b = blockIdx.x;  // 0..287 = L*96 + ks*8 + nt
    const int L = b / 96;
    const int rem = b % 96;
    const int ks = rem / 8, nt = rem % 8;
    const int lane = threadIdx.x;
    const int kb = ks * 32 + (lane >> 4) * 8;
    const int n = nt * 16 + (lane & 15);
    unsigned short v[8];
#pragma unroll
    for (int j = 0; j < 8; ++j) {
        const int k = kb + j;
        float w = 0.f;
        if (L == 0) {
            if (k < 128)      w = (n < 64) ? Wp_l[k * 64 + n] : 0.f;
            else if (k < 256) w = (n < 64) ? 0.f : Wn_l[(k - 128) * 64 + (n - 64)];
            else              w = (n < 64) ? Wp_r[(k - 256) * 64 + n]
                                           : Wn_r[(k - 256) * 64 + (n - 64)];
        } else {
            const float* WLp = Wl_pos + (size_t)(L - 1) * 128 * 64;
            const float* WLn = Wl_neg + (size_t)(L - 1) * 128 * 64;
            const float* WRp = Wr_pos + (size_t)(L - 1) * 64 * 64;
            const float* WRn = Wr_neg + (size_t)(L - 1) * 64 * 64;
            if (k < 64)       w = (n < 64) ? WLp[k * 64 + n] : 0.f;
            else if (k < 128) w = (n < 64) ? 0.f : WLn[(k - 64) * 64 + (n - 64)];
            else if (k < 192) w = (n < 64) ? 0.f : WLn[(64 + k - 128) * 64 + (n - 64)];
            else if (k < 256) w = (n < 64) ? WLp[(64 + k - 192) * 64 + n] : 0.f;
            else if (k < 320) w = (n < 64) ? WRp[(k - 256) * 64 + n] : 0.f;
            else              w = (n < 64) ? 0.f : WRn[(k - 320) * 64 + (n - 64)];
        }
        v[j] = f2bf(w);
    }
    unsigned short* dst = Wpk + (size_t)b * 512 + lane * 8;
#pragma unroll
    for (int j = 0; j < 8; ++j) dst[j] = v[j];
}

__global__ void bcat_kernel(const float* __restrict__ bp, const float* __restrict__ bn,
                            const float* __restrict__ b_pos, const float* __restrict__ b_neg,
                            float* __restrict__ bcat) {
    int t = threadIdx.x;  // 384
    int L = t >> 7, n = t & 127;
    float v;
    if (L == 0) v = (n < 64) ? bp[n] : bn[n - 64];
    else        v = (n < 64) ? b_pos[(L - 1) * 64 + n] : b_neg[(L - 1) * 64 + (n - 64)];
    bcat[t] = v;
}

// ---------------- MFMA GEMM: z = tanh([aggp|aggn|feat] @ Wcat + bcat) ----------------
// Block = 4 waves, 64 rows; wave -> 16 rows, full 128 cols (8 n-tiles).
// A-frag: lane holds A[r0+(lane&15)][kcol + (lane>>4)*8 + j]  (m120-verified layout)
// B-frag: from packed buffer (built to match)
// C/D:    col = lane&15, row = r0 + (lane>>4)*4 + reg        (m89-verified layout)
// In-place safe: block reads only its own 64 rows before its stores.
template <bool XF32, bool OUTF32>
__global__ __launch_bounds__(256) void gemm_kernel(
    const unsigned short* __restrict__ aggp, const unsigned short* __restrict__ aggn,
    const void* __restrict__ featv, const unsigned short* __restrict__ Wpk,
    const float* __restrict__ bcat, void* __restrict__ outv, int nN) {
    const int t = threadIdx.x;
    const int wave = __builtin_amdgcn_readfirstlane(t >> 6);
    const int lane = t & 63;
    const int r0 = blockIdx.x * 64 + wave * 16;
    int rowA = r0 + (lane & 15);
    if (rowA >= nN) rowA = nN - 1;  // clamp loads; stores guarded
    const int koff = (lane >> 4) * 8;

    f32x4 acc[8];
#pragma unroll
    for (int i = 0; i < 8; ++i) acc[i] = (f32x4){0.f, 0.f, 0.f, 0.f};

#pragma unroll
    for (int ks = 0; ks < 12; ++ks) {
        const int kcol = (ks & 3) * 32 + koff;
        bf16x8 a;
        if (ks < 4) {
            a = *(const bf16x8*)(aggp + (size_t)rowA * CH + kcol);
        } else if (ks < 8) {
            a = *(const bf16x8*)(aggn + (size_t)rowA * CH + kcol);
        } else if (XF32) {
            const float* p = (const float*)featv + (size_t)rowA * CH + kcol;
            const float4 u0 = *(const float4*)(p);
            const float4 u1 = *(const float4*)(p + 4);
            union { bf16x8 v; unsigned short u[8]; } au;
            au.u[0] = f2bf(u0.x); au.u[1] = f2bf(u0.y);
            au.u[2] = f2bf(u0.z); au.u[3] = f2bf(u0.w);
            au.u[4] = f2bf(u1.x); au.u[5] = f2bf(u1.y);
            au.u[6] = f2bf(u1.z); au.u[7] = f2bf(u1.w);
            a = au.v;
        } else {
            a = *(const bf16x8*)((const unsigned short*)featv + (size_t)rowA * CH + kcol);
        }
        const unsigned short* wb = Wpk + (size_t)(ks * 8) * 512 + lane * 8;
#pragma unroll
        for (int nt = 0; nt < 8; ++nt) {
            const bf16x8 bfr = *(const bf16x8*)(wb + nt * 512);
            acc[nt] = __builtin_amdgcn_mfma_f32_16x16x32_bf16(a, bfr, acc[nt], 0, 0, 0);
        }
    }

    const int col0 = lane & 15;
    const int rq = (lane >> 4) * 4;
#pragma unroll
    for (int nt = 0; nt < 8; ++nt) {
        const int col = nt * 16 + col0;
        const float bias = bcat[col];
#pragma unroll
        for (int r = 0; r < 4; ++r) {
            const int row = r0 + rq + r;
            if (row < nN) {
                const float v = fast_tanh(acc[nt][r] + bias);
                if (OUTF32) ((float*)outv)[(size_t)row * CH + col] = v;
                else ((unsigned short*)outv)[(size_t)row * CH + col] = f2bf(v);
            }
        }
    }
}

// ---------------- launch ----------------
extern "C" void kernel_launch(void* const* d_in, const int* in_sizes, int n_in,
                              void* d_out, int out_size, void* d_ws, size_t ws_size,
                              hipStream_t stream) {
    const float* x      = (const float*)d_in[0];
    const int*   pe     = (const int*)d_in[1];  // [2][E] src,dst
    const int*   ne     = (const int*)d_in[2];
    const float* Wp_l   = (const float*)d_in[3];
    const float* Wp_r   = (const float*)d_in[4];
    const float* bp     = (const float*)d_in[5];
    const float* Wn_l   = (const float*)d_in[6];
    const float* Wn_r   = (const float*)d_in[7];
    const float* bn     = (const float*)d_in[8];
    const float* Wl_pos = (const float*)d_in[9];
    const float* Wr_pos = (const float*)d_in[10];
    const float* b_pos  = (const float*)d_in[11];
    const float* Wl_neg = (const float*)d_in[12];
    const float* Wr_neg = (const float*)d_in[13];
    const float* b_neg  = (const float*)d_in[14];

    const int E = in_sizes[1] / 2;
    const int n = in_sizes[0] / CH;

    // workspace layout
    unsigned short* A    = (unsigned short*)d_ws;   // n*128 bf16
    unsigned short* B    = A + (size_t)n * CH;
    unsigned short* C    = B + (size_t)n * CH;
    unsigned short* Wpk  = C + (size_t)n * CH;      // 3*96*512 = 147456
    float* bcat  = (float*)(Wpk + 147456);          // 384
    int* cnt_p   = (int*)(bcat + 384);              // n
    int* cnt_n   = cnt_p + n;
    int* row_p   = cnt_n + n;                       // n+1
    int* row_n   = row_p + n + 1;
    int* cur_p   = row_n + n + 1;                   // n
    int* cur_n   = cur_p + n;
    int* csr_p   = cur_n + n;                       // E
    int* csr_n   = csr_p + E;                       // E
    int* partials = csr_n + E;                      // 512

    hipMemsetAsync(cnt_p, 0, (size_t)2 * n * sizeof(int), stream);

    const int eb = 256, eg2 = (2 * E + eb - 1) / eb;
    const int nb = (n + SCAN_CHUNK - 1) / SCAN_CHUNK;

    count_kernel<<<eg2, eb, 0, stream>>>(pe + E, ne + E, cnt_p, cnt_n, E);
    wpack_kernel<<<288, 64, 0, stream>>>(Wp_l, Wp_r, Wn_l, Wn_r,
                                         Wl_pos, Wr_pos, Wl_neg, Wr_neg, Wpk);
    bcat_kernel<<<1, 384, 0, stream>>>(bp, bn, b_pos, b_neg, bcat);
    partial_kernel<<<dim3(nb, 2), SCAN_T, 0, stream>>>(cnt_p, n, partials);
    scan_partials_kernel<<<dim3(1, 2), 256, 0, stream>>>(partials, nb);
    scan_apply_kernel<<<dim3(nb, 2), SCAN_T, 0, stream>>>(cnt_p, n, partials, row_p, cur_p, E);
    fill_kernel<<<eg2, eb, 0, stream>>>(pe, ne, cur_p, cur_n, csr_p, csr_n, E);

    const dim3 agrid((n + 1) / 2), ablock(256);
    const dim3 ggrid((n + 63) / 64), gblock(256);

    // L0: agg(x) -> A,B ; gemm(A,B,x) -> z1 in A
    agg_kernel<true><<<agrid, ablock, 0, stream>>>(
        x, (unsigned*)A, (unsigned*)B, row_p, csr_p, row_n, csr_n, n);
    gemm_kernel<true, false><<<ggrid, gblock, 0, stream>>>(
        A, B, x, Wpk, bcat, A, n);
    // L1: agg(A) -> B,C ; gemm(B,C,A) -> z2 in B
    agg_kernel<false><<<agrid, ablock, 0, stream>>>(
        A, (unsigned*)B, (unsigned*)C, row_p, csr_p, row_n, csr_n, n);
    gemm_kernel<false, false><<<ggrid, gblock, 0, stream>>>(
        B, C, A, Wpk + 96 * 512, bcat + 128, B, n);
    // L2: agg(B) -> A,C ; gemm(A,C,B) -> d_out fp32
    agg_kernel<false><<<agrid, ablock, 0, stream>>>(
        B, (unsigned*)A, (unsigned*)C, row_p, csr_p, row_n, csr_n, n);
    gemm_kernel<false, true><<<ggrid, gblock, 0, stream>>>(
        A, C, B, Wpk + 2 * 96 * 512, bcat + 256, d_out, n);
}